// Round 6
// baseline (467.771 us; speedup 1.0000x reference)
//
#include <hip/hip_runtime.h>
#include <hip/hip_bf16.h>

// ---------------- problem constants ----------------
constexpr int NV = 16384;   // 16*1024 z vectors
constexpr int D  = 128;     // embed dim
constexpr int NE = 8192;    // codebook size
constexpr float DECAY = 0.99f;
constexpr float BETA  = 1.0f;
constexpr float EPS   = 1e-5f;
constexpr float LO_SCALE     = 4096.0f;        // 2^12: keeps f16 lo-part normal
constexpr float INV_LO_SCALE = 1.0f / 4096.0f;

// distance-kernel geometry
constexpr int Q = 8;                       // code slices (grid.y)
constexpr int CODES_PER_Q = NE / Q;        // 1024
constexpr int TILE_C = 32;                 // codes per LDS tile
constexpr int TILES = CODES_PER_Q / TILE_C;// 32
constexpr int BZ = 128;                    // z rows per block (4 waves x 32 rows)
constexpr int NCAND = Q * 2;               // refine candidates per row (16)

// ---------------- ws layout (float units) ----------------
constexpr size_t WS_Z2    = 0;                            // NV x 256 f16 = NV*128 floats
constexpr size_t WS_E2    = WS_Z2 + (size_t)NV * 128;     // NE x 256 f16 = NE*128 floats
constexpr size_t WS_EN2   = WS_E2 + (size_t)NE * 128;     // NE (fp32, round-1 replica)
constexpr size_t WS_MINI2 = WS_EN2 + NE;                  // NV*NCAND (int)
// aliases over z2 region (z2 dead once k_dist finishes)
constexpr size_t WS_BINS  = WS_Z2;                        // NE
constexpr size_t WS_ESUM  = WS_BINS + NE;                 // NE*D
constexpr size_t WS_LPART = WS_ESUM + (size_t)NE * D;     // 4096

// ---------------- out layout (float units) ----------------
constexpr size_t OUT_ZQ   = 0;                         // NV*D
constexpr size_t OUT_LOSS = OUT_ZQ + (size_t)NV*D;     // 1
constexpr size_t OUT_IDX  = OUT_LOSS + 1;              // NV
constexpr size_t OUT_EMB  = OUT_IDX + NV;              // NE*D
constexpr size_t OUT_CS   = OUT_EMB + (size_t)NE*D;    // NE
constexpr size_t OUT_EAVG = OUT_CS + NE;               // NE*D

using half8  = __attribute__((ext_vector_type(8))) _Float16;
using half2v = __attribute__((ext_vector_type(2))) _Float16;
using f32x4  = __attribute__((ext_vector_type(4))) float;

__device__ inline float waveReduceSum(float v) {
    #pragma unroll
    for (int o = 32; o > 0; o >>= 1) v += __shfl_xor(v, o, 64);
    return v;
}

// async global->LDS, 16B per lane; LDS dest = wave-uniform base + lane*16 (linear)
__device__ inline void gload_lds16(const void* g, void* s) {
    __builtin_amdgcn_global_load_lds(
        (const __attribute__((address_space(1))) unsigned int*)g,
        (__attribute__((address_space(3))) unsigned int*)s, 16, 0, 0);
}

// ---------- prep: normalize z rows, split to f16 hi/lo -> z2[NV][256] ----------
__global__ void k_prep_z(const float* __restrict__ z, _Float16* __restrict__ z2) {
    int tid = threadIdx.x;
    int l = tid & 63;
    int row = blockIdx.x * 4 + (tid >> 6);
    const float2 v = *reinterpret_cast<const float2*>(&z[(size_t)row * D + l * 2]);
    float s = waveReduceSum(v.x * v.x + v.y * v.y);
    float inv = 1.0f / fmaxf(sqrtf(s), 1e-12f);
    float zn0 = v.x * inv, zn1 = v.y * inv;
    _Float16 h0 = (_Float16)zn0, h1 = (_Float16)zn1;
    _Float16 l0 = (_Float16)((zn0 - (float)h0) * LO_SCALE);
    _Float16 l1 = (_Float16)((zn1 - (float)h1) * LO_SCALE);
    _Float16* zr = &z2[(size_t)row * 256];
    half2v hh = {h0, h1}, lv = {l0, l1};
    *reinterpret_cast<half2v*>(&zr[l * 2])       = hh;
    *reinterpret_cast<half2v*>(&zr[128 + l * 2]) = lv;
}

// ---------- prep: codebook split to f16 hi/lo -> e2[NE][256]; |e|^2 fp32 (R1 replica) ----------
__global__ void k_prep_e(const float* __restrict__ emb, _Float16* __restrict__ e2,
                         float* __restrict__ en2) {
    int tid = threadIdx.x;
    int l = tid & 63;
    int row = blockIdx.x * 4 + (tid >> 6);
    const float2 v = *reinterpret_cast<const float2*>(&emb[(size_t)row * D + l * 2]);
    float s = waveReduceSum(v.x * v.x + v.y * v.y);   // bitwise = round-1 k_enorm2
    if (l == 0) en2[row] = s;
    _Float16 h0 = (_Float16)v.x, h1 = (_Float16)v.y;
    _Float16 l0 = (_Float16)((v.x - (float)h0) * LO_SCALE);
    _Float16 l1 = (_Float16)((v.y - (float)h1) * LO_SCALE);
    _Float16* er = &e2[(size_t)row * 256];
    half2v hh = {h0, h1}, lv = {l0, l1};
    *reinterpret_cast<half2v*>(&er[l * 2])       = hh;
    *reinterpret_cast<half2v*>(&er[128 + l * 2]) = lv;
}

// ---------- MFMA approximate distance + top-2 per (row, slice) ----------
// 256 thr = 4 waves; wave owns 32 z rows (2 rowfrags). A (z hi/lo, K=256) in regs.
// e-tiles (32 codes x 256 k f16 = 16 KB) double-buffered (36 KB LDS -> 4 blocks/CU),
// staged via global_load_lds with PRE-SWIZZLED per-lane source (XOR involution).
// SIX independent MFMA accumulator chains, round-robin issue -> no RAW pipe stalls.
// dot ~= accA + (accB1+accB2)/4096 (err ~5e-7); re-ranked by fp32 replica in k_gather.
__global__ __launch_bounds__(256, 4) void k_dist(
        const _Float16* __restrict__ z2, const _Float16* __restrict__ e2,
        const float* __restrict__ en2, int* __restrict__ minI2) {
    __shared__ _Float16 eb[2][TILE_C * 256];   // 2 x 16 KB
    __shared__ float en2s[CODES_PER_Q];        // 4 KB

    const int tid = threadIdx.x;
    const int w  = tid >> 6;
    const int l  = tid & 63;
    const int lg = l >> 4;      // k-group (0..3)
    const int ll = l & 15;      // low lane: A-row / B-col index
    const int zb = blockIdx.x * BZ;
    const int q  = blockIdx.y;
    const int cbase0 = q * CODES_PER_Q;

    // A fragments: a[rowfrag][kfrag], k = kf*32 + lg*8 + j (same convention as B)
    half8 a[2][8];
    #pragma unroll
    for (int rf = 0; rf < 2; ++rf) {
        const size_t row = (size_t)(zb + w * 32 + rf * 16 + ll);
        #pragma unroll
        for (int kf = 0; kf < 8; ++kf)
            a[rf][kf] = *reinterpret_cast<const half8*>(&z2[row * 256 + kf * 32 + lg * 8]);
    }

    for (int i = tid; i < CODES_PER_Q; i += 256) en2s[i] = en2[cbase0 + i];

    // stage tile t into buffer b: 1024 16B-chunks; wave w call i covers chunks
    // (w*4+i)*64 + lane. LDS linear; global src pre-swizzled (j ^= row&7).
    auto stage = [&](int b, int t) {
        const char* tbase = reinterpret_cast<const char*>(&e2[(size_t)(cbase0 + t * TILE_C) * 256]);
        #pragma unroll
        for (int i = 0; i < 4; ++i) {
            int c = (w * 4 + i) * 64 + l;
            int row = c >> 5, j = c & 31;
            const char* src = tbase + row * 512 + ((j ^ (row & 7)) * 16);
            gload_lds16(src, &eb[b][(size_t)(w * 4 + i) * 512]);
        }
    };

    stage(0, 0);

    float bV1[8], bV2[8];
    int   bI1[8], bI2[8];
    #pragma unroll
    for (int i = 0; i < 8; ++i) { bV1[i] = 3.4e38f; bV2[i] = 3.4e38f; bI1[i] = 0; bI2[i] = 0; }

    int cur = 0;
    for (int t = 0; t < TILES; ++t) {
        __syncthreads();                       // vmcnt drained: eb[cur] staged & visible
        if (t + 1 < TILES) stage(cur ^ 1, t + 1);   // async prefetch into other buffer

        const char* base = reinterpret_cast<const char*>(&eb[cur][0]);
        #pragma unroll
        for (int n = 0; n < 2; ++n) {          // colfrag: 16 codes each
            f32x4 accA[2], accB1[2], accB2[2];
            #pragma unroll
            for (int rf = 0; rf < 2; ++rf) {
                accA[rf]  = f32x4{0.f, 0.f, 0.f, 0.f};
                accB1[rf] = f32x4{0.f, 0.f, 0.f, 0.f};
                accB2[rf] = f32x4{0.f, 0.f, 0.f, 0.f};
            }
            const int brow = n * 16 + ll;
            const char* rbase = base + brow * 512;
            const int swz = brow & 7;
            #pragma unroll
            for (int kq = 0; kq < 4; ++kq) {
                half8 bh = *reinterpret_cast<const half8*>(rbase + (((kq * 4 + lg) ^ swz) * 16));
                half8 bl = *reinterpret_cast<const half8*>(rbase + ((((kq + 4) * 4 + lg) ^ swz) * 16));
                // round-robin over 6 independent chains: reuse distance 6 issues
                accA[0]  = __builtin_amdgcn_mfma_f32_16x16x32_f16(a[0][kq],     bh, accA[0],  0, 0, 0);
                accA[1]  = __builtin_amdgcn_mfma_f32_16x16x32_f16(a[1][kq],     bh, accA[1],  0, 0, 0);
                accB1[0] = __builtin_amdgcn_mfma_f32_16x16x32_f16(a[0][kq + 4], bh, accB1[0], 0, 0, 0);
                accB1[1] = __builtin_amdgcn_mfma_f32_16x16x32_f16(a[1][kq + 4], bh, accB1[1], 0, 0, 0);
                accB2[0] = __builtin_amdgcn_mfma_f32_16x16x32_f16(a[0][kq],     bl, accB2[0], 0, 0, 0);
                accB2[1] = __builtin_amdgcn_mfma_f32_16x16x32_f16(a[1][kq],     bl, accB2[1], 0, 0, 0);
            }
            const int code = cbase0 + t * TILE_C + n * 16 + ll;
            const float e2v = en2s[t * TILE_C + n * 16 + ll];
            #pragma unroll
            for (int rf = 0; rf < 2; ++rf) {
                #pragma unroll
                for (int r = 0; r < 4; ++r) {
                    float b12 = accB1[rf][r] + accB2[rf][r];
                    float dot = fmaf(b12, INV_LO_SCALE, accA[rf][r]);
                    float s = fmaf(-2.0f, dot, e2v);
                    int bi = rf * 4 + r;
                    // branchless top-2 insert (same semantics as if/elif chain)
                    bool c1 = s < bV1[bi];
                    float sv = c1 ? bV1[bi] : s;
                    int   si = c1 ? bI1[bi] : code;
                    bV1[bi] = c1 ? s    : bV1[bi];
                    bI1[bi] = c1 ? code : bI1[bi];
                    bool c2 = sv < bV2[bi];
                    bV2[bi] = c2 ? sv : bV2[bi];
                    bI2[bi] = c2 ? si : bI2[bi];
                }
            }
        }
        cur ^= 1;
    }

    // cross-lane top-2 merge (disjoint code sets per step)
    #pragma unroll
    for (int bi = 0; bi < 8; ++bi) {
        float v1 = bV1[bi], v2 = bV2[bi];
        int   i1 = bI1[bi], i2 = bI2[bi];
        #pragma unroll
        for (int m = 1; m < 16; m <<= 1) {
            float w1 = __shfl_xor(v1, m, 64);
            int   j1 = __shfl_xor(i1, m, 64);
            float w2 = __shfl_xor(v2, m, 64);
            int   j2 = __shfl_xor(i2, m, 64);
            bool oth = (w1 < v1) || (w1 == v1 && j1 < i1);
            if (oth) {
                bool keep = (v1 < w2) || (v1 == w2 && i1 < j2);
                v2 = keep ? v1 : w2; i2 = keep ? i1 : j2;
                v1 = w1; i1 = j1;
            } else {
                bool repl = (w1 < v2) || (w1 == v2 && j1 < i2);
                v2 = repl ? w1 : v2; i2 = repl ? j1 : i2;
            }
        }
        if (ll == 0) {
            int rf = bi >> 2, r = bi & 3;
            int zrow = zb + w * 32 + rf * 16 + lg * 4 + r;   // C/D: row=(lane>>4)*4+reg
            size_t o = ((size_t)zrow * Q + q) * 2;
            minI2[o] = i1; minI2[o + 1] = i2;
        }
    }
}

// ---------- round-1-replica fp32 refine over 16 candidates + gather + loss + segsums ----------
__global__ void k_gather(const float* __restrict__ z, const float* __restrict__ emb,
                         const float* __restrict__ en2, const int* __restrict__ minI2,
                         float* __restrict__ outZq, float* __restrict__ outIdx,
                         float* __restrict__ bins, float* __restrict__ esum,
                         float* __restrict__ lossPart) {
    __shared__ float zsh[4][128];
    int tid = threadIdx.x;
    int wave = tid >> 6, lane = tid & 63;
    int zr = blockIdx.x * 4 + wave;

    // zn exactly as round-1 k_norm_z (fp32 butterfly, same ops)
    const float2 zv = *reinterpret_cast<const float2*>(&z[(size_t)zr * D + lane * 2]);
    float s = waveReduceSum(zv.x * zv.x + zv.y * zv.y);
    float inv = 1.0f / fmaxf(sqrtf(s), 1e-12f);
    float znx = zv.x * inv, zny = zv.y * inv;
    zsh[wave][lane * 2]     = znx;
    zsh[wave][lane * 2 + 1] = zny;
    __syncthreads();

    // 16 lanes re-score the 16 candidates with round-1's exact arithmetic:
    // sequential fmaf chain k=0..127, then s = fmaf(-2, dot, en2[c]).
    float cv = 3.4e38f; int ci = 0x7fffffff;
    if (lane < NCAND) {
        ci = minI2[(size_t)zr * NCAND + lane];
        const float* er = &emb[(size_t)ci * D];
        float dot = 0.0f;
        #pragma unroll 8
        for (int k = 0; k < 128; ++k) dot = fmaf(zsh[wave][k], er[k], dot);
        cv = fmaf(-2.0f, dot, en2[ci]);
    }
    float bv = cv; int bi = ci;
    #pragma unroll
    for (int m = 1; m < NCAND; m <<= 1) {
        float ov = __shfl_xor(bv, m, 64);
        int   oi = __shfl_xor(bi, m, 64);
        if (ov < bv || (ov == bv && oi < bi)) { bv = ov; bi = oi; }
    }
    bi = __shfl(bi, 0, 64);    // broadcast winner to all 64 lanes
    if (lane == 0) outIdx[zr] = (float)bi;

    float2 e = *reinterpret_cast<const float2*>(&emb[(size_t)bi * D + lane * 2]);
    *reinterpret_cast<float2*>(&outZq[(size_t)zr * D + lane * 2]) = e;

    float dx = e.x - znx, dy = e.y - zny;
    float ls = waveReduceSum(dx * dx + dy * dy);

    if (lane == 0) atomicAdd(&bins[bi], 1.0f);
    atomicAdd(&esum[(size_t)bi * D + lane * 2 + 0], znx);
    atomicAdd(&esum[(size_t)bi * D + lane * 2 + 1], zny);

    __shared__ float part[4];
    if (lane == 0) part[wave] = ls;
    __syncthreads();
    if (tid == 0) lossPart[blockIdx.x] = (part[0] + part[1]) + (part[2] + part[3]);
}

// ---------- final loss reduce ----------
__global__ void k_loss(const float* __restrict__ lossPart, float* __restrict__ outLoss) {
    int tid = threadIdx.x;
    float s = 0.0f;
    for (int i = tid; i < 4096; i += 256) s += lossPart[i];
    s = waveReduceSum(s);
    __shared__ float p[4];
    if ((tid & 63) == 0) p[tid >> 6] = s;
    __syncthreads();
    if (tid == 0) outLoss[0] = BETA * ((p[0] + p[1]) + (p[2] + p[3])) / (float)((size_t)NV * D);
}

// ---------- per-code EMA update + renormalize ----------
__global__ void k_codebook(const float* __restrict__ emb, const float* __restrict__ csz,
                           const float* __restrict__ eavg, const float* __restrict__ bins,
                           const float* __restrict__ esum,
                           float* __restrict__ outEmb, float* __restrict__ outCs,
                           float* __restrict__ outEavg) {
    int tid = threadIdx.x;
    int wave = tid >> 6, lane = tid & 63;
    int n = blockIdx.x * 4 + wave;

    float b = bins[n];
    if (lane == 0) outCs[n] = csz[n] * DECAY + (1.0f - DECAY) * b;

    float2 es = *reinterpret_cast<const float2*>(&esum[(size_t)n * D + lane * 2]);
    float invb = 1.0f / (b + EPS);
    float mx = es.x * invb, my = es.y * invb;
    float ss = waveReduceSum(mx * mx + my * my);
    float invn = 1.0f / fmaxf(sqrtf(ss), 1e-12f);

    float2 er = *reinterpret_cast<const float2*>(&emb[(size_t)n * D + lane * 2]);
    float enx = (b == 0.0f) ? er.x : mx * invn;
    float eny = (b == 0.0f) ? er.y : my * invn;

    float2 ea = *reinterpret_cast<const float2*>(&eavg[(size_t)n * D + lane * 2]);
    float nax = ea.x * DECAY + (1.0f - DECAY) * enx;
    float nay = ea.y * DECAY + (1.0f - DECAY) * eny;
    float2 no; no.x = nax; no.y = nay;
    *reinterpret_cast<float2*>(&outEavg[(size_t)n * D + lane * 2]) = no;

    float ss2 = waveReduceSum(nax * nax + nay * nay);
    float inv2 = 1.0f / fmaxf(sqrtf(ss2), 1e-12f);
    float2 ne; ne.x = nax * inv2; ne.y = nay * inv2;
    *reinterpret_cast<float2*>(&outEmb[(size_t)n * D + lane * 2]) = ne;
}

extern "C" void kernel_launch(void* const* d_in, const int* in_sizes, int n_in,
                              void* d_out, int out_size, void* d_ws, size_t ws_size,
                              hipStream_t stream) {
    (void)in_sizes; (void)n_in; (void)out_size; (void)ws_size;
    const float* z    = (const float*)d_in[0];
    const float* emb  = (const float*)d_in[1];
    const float* csz  = (const float*)d_in[2];
    const float* eavg = (const float*)d_in[3];
    float* out = (float*)d_out;
    float* ws  = (float*)d_ws;

    _Float16* z2   = (_Float16*)(ws + WS_Z2);
    _Float16* e2   = (_Float16*)(ws + WS_E2);
    float*  en2    = ws + WS_EN2;
    int*    minI2  = (int*)(ws + WS_MINI2);
    float*  bins   = ws + WS_BINS;
    float*  esum   = ws + WS_ESUM;
    float*  lpart  = ws + WS_LPART;

    k_prep_z<<<NV / 4, 256, 0, stream>>>(z, z2);
    k_prep_e<<<NE / 4, 256, 0, stream>>>(emb, e2, en2);
    k_dist<<<dim3(NV / BZ, Q), 256, 0, stream>>>(z2, e2, en2, minI2);
    // bins+esum zeroing must follow k_dist (they alias the z2 region)
    hipMemsetAsync(bins, 0, ((size_t)NE + (size_t)NE * D) * sizeof(float), stream);
    k_gather<<<NV / 4, 256, 0, stream>>>(z, emb, en2, minI2,
                                         out + OUT_ZQ, out + OUT_IDX, bins, esum, lpart);
    k_loss<<<1, 256, 0, stream>>>(lpart, out + OUT_LOSS);
    k_codebook<<<NE / 4, 256, 0, stream>>>(emb, csz, eavg, bins, esum,
                                           out + OUT_EMB, out + OUT_CS, out + OUT_EAVG);
}

// Round 7
// 188.912 us; speedup vs baseline: 2.4761x; 2.4761x over previous
//
#include <hip/hip_runtime.h>
#include <hip/hip_bf16.h>

// ---------------- problem constants ----------------
constexpr int NV = 16384;   // 16*1024 z vectors
constexpr int D  = 128;     // embed dim
constexpr int NE = 8192;    // codebook size
constexpr float DECAY = 0.99f;
constexpr float BETA  = 1.0f;
constexpr float EPS   = 1e-5f;
constexpr float LO_SCALE     = 4096.0f;        // 2^12: keeps f16 lo-part normal
constexpr float INV_LO_SCALE = 1.0f / 4096.0f;

// distance-kernel geometry
constexpr int Q = 8;                       // code slices (grid.y)
constexpr int CODES_PER_Q = NE / Q;        // 1024
constexpr int TILE_C = 32;                 // codes per LDS tile
constexpr int TILES = CODES_PER_Q / TILE_C;// 32
constexpr int BZ = 128;                    // z rows per block (4 waves x 32 rows)
constexpr int NCAND = Q * 2;               // refine candidates per row (16)

// ---------------- ws layout (float units) ----------------
constexpr size_t WS_Z2    = 0;                            // NV x 256 f16 = NV*128 floats
constexpr size_t WS_E2    = WS_Z2 + (size_t)NV * 128;     // NE x 256 f16 = NE*128 floats
constexpr size_t WS_EN2   = WS_E2 + (size_t)NE * 128;     // NE (fp32, round-1 replica)
constexpr size_t WS_MINI2 = WS_EN2 + NE;                  // NV*NCAND (int)
// aliases over z2 region (z2 dead once k_dist finishes)
constexpr size_t WS_BINS  = WS_Z2;                        // NE
constexpr size_t WS_ESUM  = WS_BINS + NE;                 // NE*D
constexpr size_t WS_LPART = WS_ESUM + (size_t)NE * D;     // 4096

// ---------------- out layout (float units) ----------------
constexpr size_t OUT_ZQ   = 0;                         // NV*D
constexpr size_t OUT_LOSS = OUT_ZQ + (size_t)NV*D;     // 1
constexpr size_t OUT_IDX  = OUT_LOSS + 1;              // NV
constexpr size_t OUT_EMB  = OUT_IDX + NV;              // NE*D
constexpr size_t OUT_CS   = OUT_EMB + (size_t)NE*D;    // NE
constexpr size_t OUT_EAVG = OUT_CS + NE;               // NE*D

using half8  = __attribute__((ext_vector_type(8))) _Float16;
using half2v = __attribute__((ext_vector_type(2))) _Float16;
using f32x4  = __attribute__((ext_vector_type(4))) float;

__device__ inline float waveReduceSum(float v) {
    #pragma unroll
    for (int o = 32; o > 0; o >>= 1) v += __shfl_xor(v, o, 64);
    return v;
}

// async global->LDS, 16B per lane; LDS dest = wave-uniform base + lane*16 (linear)
__device__ inline void gload_lds16(const void* g, void* s) {
    __builtin_amdgcn_global_load_lds(
        (const __attribute__((address_space(1))) unsigned int*)g,
        (__attribute__((address_space(3))) unsigned int*)s, 16, 0, 0);
}

// ---------- prep: normalize z rows, split to f16 hi/lo -> z2[NV][256] ----------
__global__ void k_prep_z(const float* __restrict__ z, _Float16* __restrict__ z2) {
    int tid = threadIdx.x;
    int l = tid & 63;
    int row = blockIdx.x * 4 + (tid >> 6);
    const float2 v = *reinterpret_cast<const float2*>(&z[(size_t)row * D + l * 2]);
    float s = waveReduceSum(v.x * v.x + v.y * v.y);
    float inv = 1.0f / fmaxf(sqrtf(s), 1e-12f);
    float zn0 = v.x * inv, zn1 = v.y * inv;
    _Float16 h0 = (_Float16)zn0, h1 = (_Float16)zn1;
    _Float16 l0 = (_Float16)((zn0 - (float)h0) * LO_SCALE);
    _Float16 l1 = (_Float16)((zn1 - (float)h1) * LO_SCALE);
    _Float16* zr = &z2[(size_t)row * 256];
    half2v hh = {h0, h1}, lv = {l0, l1};
    *reinterpret_cast<half2v*>(&zr[l * 2])       = hh;
    *reinterpret_cast<half2v*>(&zr[128 + l * 2]) = lv;
}

// ---------- prep: codebook split to f16 hi/lo -> e2[NE][256]; |e|^2 fp32 (R1 replica) ----------
__global__ void k_prep_e(const float* __restrict__ emb, _Float16* __restrict__ e2,
                         float* __restrict__ en2) {
    int tid = threadIdx.x;
    int l = tid & 63;
    int row = blockIdx.x * 4 + (tid >> 6);
    const float2 v = *reinterpret_cast<const float2*>(&emb[(size_t)row * D + l * 2]);
    float s = waveReduceSum(v.x * v.x + v.y * v.y);   // bitwise = round-1 k_enorm2
    if (l == 0) en2[row] = s;
    _Float16 h0 = (_Float16)v.x, h1 = (_Float16)v.y;
    _Float16 l0 = (_Float16)((v.x - (float)h0) * LO_SCALE);
    _Float16 l1 = (_Float16)((v.y - (float)h1) * LO_SCALE);
    _Float16* er = &e2[(size_t)row * 256];
    half2v hh = {h0, h1}, lv = {l0, l1};
    *reinterpret_cast<half2v*>(&er[l * 2])       = hh;
    *reinterpret_cast<half2v*>(&er[128 + l * 2]) = lv;
}

// ---------- MFMA approximate distance + top-2 per (row, slice) ----------
// 256 thr = 4 waves; wave owns 32 z rows (2 rowfrags). A (z hi/lo, K=256) in regs.
// e-tiles (32 codes x 256 k f16 = 16 KB) double-buffered (36 KB LDS -> 4 blocks/CU),
// staged via global_load_lds with PRE-SWIZZLED per-lane source (XOR involution).
// SIX independent MFMA accumulator chains, round-robin issue -> no RAW pipe stalls.
// launch_bounds min 2 waves/EU: R6's (256,4) forced a 128-reg cap -> spill storm
// (WRITE_SIZE 589 MB, VGPR 64). (256,2) keeps R5's spill-free regime; ~110 VGPR
// still fits 4 waves/SIMD naturally.
// dot ~= accA + (accB1+accB2)/4096 (err ~5e-7); re-ranked by fp32 replica in k_gather.
__global__ __launch_bounds__(256, 2) void k_dist(
        const _Float16* __restrict__ z2, const _Float16* __restrict__ e2,
        const float* __restrict__ en2, int* __restrict__ minI2) {
    __shared__ _Float16 eb[2][TILE_C * 256];   // 2 x 16 KB
    __shared__ float en2s[CODES_PER_Q];        // 4 KB

    const int tid = threadIdx.x;
    const int w  = tid >> 6;
    const int l  = tid & 63;
    const int lg = l >> 4;      // k-group (0..3)
    const int ll = l & 15;      // low lane: A-row / B-col index
    const int zb = blockIdx.x * BZ;
    const int q  = blockIdx.y;
    const int cbase0 = q * CODES_PER_Q;

    // A fragments: a[rowfrag][kfrag], k = kf*32 + lg*8 + j (same convention as B)
    half8 a[2][8];
    #pragma unroll
    for (int rf = 0; rf < 2; ++rf) {
        const size_t row = (size_t)(zb + w * 32 + rf * 16 + ll);
        #pragma unroll
        for (int kf = 0; kf < 8; ++kf)
            a[rf][kf] = *reinterpret_cast<const half8*>(&z2[row * 256 + kf * 32 + lg * 8]);
    }

    for (int i = tid; i < CODES_PER_Q; i += 256) en2s[i] = en2[cbase0 + i];

    // stage tile t into buffer b: 1024 16B-chunks; wave w call i covers chunks
    // (w*4+i)*64 + lane. LDS linear; global src pre-swizzled (j ^= row&7).
    auto stage = [&](int b, int t) {
        const char* tbase = reinterpret_cast<const char*>(&e2[(size_t)(cbase0 + t * TILE_C) * 256]);
        #pragma unroll
        for (int i = 0; i < 4; ++i) {
            int c = (w * 4 + i) * 64 + l;
            int row = c >> 5, j = c & 31;
            const char* src = tbase + row * 512 + ((j ^ (row & 7)) * 16);
            gload_lds16(src, &eb[b][(size_t)(w * 4 + i) * 512]);
        }
    };

    stage(0, 0);

    float bV1[8], bV2[8];
    int   bI1[8], bI2[8];
    #pragma unroll
    for (int i = 0; i < 8; ++i) { bV1[i] = 3.4e38f; bV2[i] = 3.4e38f; bI1[i] = 0; bI2[i] = 0; }

    int cur = 0;
    for (int t = 0; t < TILES; ++t) {
        __syncthreads();                       // vmcnt drained: eb[cur] staged & visible
        if (t + 1 < TILES) stage(cur ^ 1, t + 1);   // async prefetch into other buffer

        const char* base = reinterpret_cast<const char*>(&eb[cur][0]);
        #pragma unroll
        for (int n = 0; n < 2; ++n) {          // colfrag: 16 codes each
            f32x4 accA[2], accB1[2], accB2[2];
            #pragma unroll
            for (int rf = 0; rf < 2; ++rf) {
                accA[rf]  = f32x4{0.f, 0.f, 0.f, 0.f};
                accB1[rf] = f32x4{0.f, 0.f, 0.f, 0.f};
                accB2[rf] = f32x4{0.f, 0.f, 0.f, 0.f};
            }
            const int brow = n * 16 + ll;
            const char* rbase = base + brow * 512;
            const int swz = brow & 7;
            #pragma unroll
            for (int kq = 0; kq < 4; ++kq) {
                half8 bh = *reinterpret_cast<const half8*>(rbase + (((kq * 4 + lg) ^ swz) * 16));
                half8 bl = *reinterpret_cast<const half8*>(rbase + ((((kq + 4) * 4 + lg) ^ swz) * 16));
                // round-robin over 6 independent chains: reuse distance 6 issues
                accA[0]  = __builtin_amdgcn_mfma_f32_16x16x32_f16(a[0][kq],     bh, accA[0],  0, 0, 0);
                accA[1]  = __builtin_amdgcn_mfma_f32_16x16x32_f16(a[1][kq],     bh, accA[1],  0, 0, 0);
                accB1[0] = __builtin_amdgcn_mfma_f32_16x16x32_f16(a[0][kq + 4], bh, accB1[0], 0, 0, 0);
                accB1[1] = __builtin_amdgcn_mfma_f32_16x16x32_f16(a[1][kq + 4], bh, accB1[1], 0, 0, 0);
                accB2[0] = __builtin_amdgcn_mfma_f32_16x16x32_f16(a[0][kq],     bl, accB2[0], 0, 0, 0);
                accB2[1] = __builtin_amdgcn_mfma_f32_16x16x32_f16(a[1][kq],     bl, accB2[1], 0, 0, 0);
            }
            const int code = cbase0 + t * TILE_C + n * 16 + ll;
            const float e2v = en2s[t * TILE_C + n * 16 + ll];
            #pragma unroll
            for (int rf = 0; rf < 2; ++rf) {
                #pragma unroll
                for (int r = 0; r < 4; ++r) {
                    float b12 = accB1[rf][r] + accB2[rf][r];
                    float dot = fmaf(b12, INV_LO_SCALE, accA[rf][r]);
                    float s = fmaf(-2.0f, dot, e2v);
                    int bi = rf * 4 + r;
                    // branchless top-2 insert (same semantics as if/elif chain)
                    bool c1 = s < bV1[bi];
                    float sv = c1 ? bV1[bi] : s;
                    int   si = c1 ? bI1[bi] : code;
                    bV1[bi] = c1 ? s    : bV1[bi];
                    bI1[bi] = c1 ? code : bI1[bi];
                    bool c2 = sv < bV2[bi];
                    bV2[bi] = c2 ? sv : bV2[bi];
                    bI2[bi] = c2 ? si : bI2[bi];
                }
            }
        }
        cur ^= 1;
    }

    // cross-lane top-2 merge (disjoint code sets per step)
    #pragma unroll
    for (int bi = 0; bi < 8; ++bi) {
        float v1 = bV1[bi], v2 = bV2[bi];
        int   i1 = bI1[bi], i2 = bI2[bi];
        #pragma unroll
        for (int m = 1; m < 16; m <<= 1) {
            float w1 = __shfl_xor(v1, m, 64);
            int   j1 = __shfl_xor(i1, m, 64);
            float w2 = __shfl_xor(v2, m, 64);
            int   j2 = __shfl_xor(i2, m, 64);
            bool oth = (w1 < v1) || (w1 == v1 && j1 < i1);
            if (oth) {
                bool keep = (v1 < w2) || (v1 == w2 && i1 < j2);
                v2 = keep ? v1 : w2; i2 = keep ? i1 : j2;
                v1 = w1; i1 = j1;
            } else {
                bool repl = (w1 < v2) || (w1 == v2 && j1 < i2);
                v2 = repl ? w1 : v2; i2 = repl ? j1 : i2;
            }
        }
        if (ll == 0) {
            int rf = bi >> 2, r = bi & 3;
            int zrow = zb + w * 32 + rf * 16 + lg * 4 + r;   // C/D: row=(lane>>4)*4+reg
            size_t o = ((size_t)zrow * Q + q) * 2;
            minI2[o] = i1; minI2[o + 1] = i2;
        }
    }
}

// ---------- round-1-replica fp32 refine over 16 candidates + gather + loss + segsums ----------
__global__ void k_gather(const float* __restrict__ z, const float* __restrict__ emb,
                         const float* __restrict__ en2, const int* __restrict__ minI2,
                         float* __restrict__ outZq, float* __restrict__ outIdx,
                         float* __restrict__ bins, float* __restrict__ esum,
                         float* __restrict__ lossPart) {
    __shared__ float zsh[4][128];
    int tid = threadIdx.x;
    int wave = tid >> 6, lane = tid & 63;
    int zr = blockIdx.x * 4 + wave;

    // zn exactly as round-1 k_norm_z (fp32 butterfly, same ops)
    const float2 zv = *reinterpret_cast<const float2*>(&z[(size_t)zr * D + lane * 2]);
    float s = waveReduceSum(zv.x * zv.x + zv.y * zv.y);
    float inv = 1.0f / fmaxf(sqrtf(s), 1e-12f);
    float znx = zv.x * inv, zny = zv.y * inv;
    zsh[wave][lane * 2]     = znx;
    zsh[wave][lane * 2 + 1] = zny;
    __syncthreads();

    // 16 lanes re-score the 16 candidates with round-1's exact arithmetic:
    // sequential fmaf chain k=0..127, then s = fmaf(-2, dot, en2[c]).
    float cv = 3.4e38f; int ci = 0x7fffffff;
    if (lane < NCAND) {
        ci = minI2[(size_t)zr * NCAND + lane];
        const float* er = &emb[(size_t)ci * D];
        float dot = 0.0f;
        #pragma unroll 8
        for (int k = 0; k < 128; ++k) dot = fmaf(zsh[wave][k], er[k], dot);
        cv = fmaf(-2.0f, dot, en2[ci]);
    }
    float bv = cv; int bi = ci;
    #pragma unroll
    for (int m = 1; m < NCAND; m <<= 1) {
        float ov = __shfl_xor(bv, m, 64);
        int   oi = __shfl_xor(bi, m, 64);
        if (ov < bv || (ov == bv && oi < bi)) { bv = ov; bi = oi; }
    }
    bi = __shfl(bi, 0, 64);    // broadcast winner to all 64 lanes
    if (lane == 0) outIdx[zr] = (float)bi;

    float2 e = *reinterpret_cast<const float2*>(&emb[(size_t)bi * D + lane * 2]);
    *reinterpret_cast<float2*>(&outZq[(size_t)zr * D + lane * 2]) = e;

    float dx = e.x - znx, dy = e.y - zny;
    float ls = waveReduceSum(dx * dx + dy * dy);

    if (lane == 0) atomicAdd(&bins[bi], 1.0f);
    atomicAdd(&esum[(size_t)bi * D + lane * 2 + 0], znx);
    atomicAdd(&esum[(size_t)bi * D + lane * 2 + 1], zny);

    __shared__ float part[4];
    if (lane == 0) part[wave] = ls;
    __syncthreads();
    if (tid == 0) lossPart[blockIdx.x] = (part[0] + part[1]) + (part[2] + part[3]);
}

// ---------- final loss reduce ----------
__global__ void k_loss(const float* __restrict__ lossPart, float* __restrict__ outLoss) {
    int tid = threadIdx.x;
    float s = 0.0f;
    for (int i = tid; i < 4096; i += 256) s += lossPart[i];
    s = waveReduceSum(s);
    __shared__ float p[4];
    if ((tid & 63) == 0) p[tid >> 6] = s;
    __syncthreads();
    if (tid == 0) outLoss[0] = BETA * ((p[0] + p[1]) + (p[2] + p[3])) / (float)((size_t)NV * D);
}

// ---------- per-code EMA update + renormalize ----------
__global__ void k_codebook(const float* __restrict__ emb, const float* __restrict__ csz,
                           const float* __restrict__ eavg, const float* __restrict__ bins,
                           const float* __restrict__ esum,
                           float* __restrict__ outEmb, float* __restrict__ outCs,
                           float* __restrict__ outEavg) {
    int tid = threadIdx.x;
    int wave = tid >> 6, lane = tid & 63;
    int n = blockIdx.x * 4 + wave;

    float b = bins[n];
    if (lane == 0) outCs[n] = csz[n] * DECAY + (1.0f - DECAY) * b;

    float2 es = *reinterpret_cast<const float2*>(&esum[(size_t)n * D + lane * 2]);
    float invb = 1.0f / (b + EPS);
    float mx = es.x * invb, my = es.y * invb;
    float ss = waveReduceSum(mx * mx + my * my);
    float invn = 1.0f / fmaxf(sqrtf(ss), 1e-12f);

    float2 er = *reinterpret_cast<const float2*>(&emb[(size_t)n * D + lane * 2]);
    float enx = (b == 0.0f) ? er.x : mx * invn;
    float eny = (b == 0.0f) ? er.y : my * invn;

    float2 ea = *reinterpret_cast<const float2*>(&eavg[(size_t)n * D + lane * 2]);
    float nax = ea.x * DECAY + (1.0f - DECAY) * enx;
    float nay = ea.y * DECAY + (1.0f - DECAY) * eny;
    float2 no; no.x = nax; no.y = nay;
    *reinterpret_cast<float2*>(&outEavg[(size_t)n * D + lane * 2]) = no;

    float ss2 = waveReduceSum(nax * nax + nay * nay);
    float inv2 = 1.0f / fmaxf(sqrtf(ss2), 1e-12f);
    float2 ne; ne.x = nax * inv2; ne.y = nay * inv2;
    *reinterpret_cast<float2*>(&outEmb[(size_t)n * D + lane * 2]) = ne;
}

extern "C" void kernel_launch(void* const* d_in, const int* in_sizes, int n_in,
                              void* d_out, int out_size, void* d_ws, size_t ws_size,
                              hipStream_t stream) {
    (void)in_sizes; (void)n_in; (void)out_size; (void)ws_size;
    const float* z    = (const float*)d_in[0];
    const float* emb  = (const float*)d_in[1];
    const float* csz  = (const float*)d_in[2];
    const float* eavg = (const float*)d_in[3];
    float* out = (float*)d_out;
    float* ws  = (float*)d_ws;

    _Float16* z2   = (_Float16*)(ws + WS_Z2);
    _Float16* e2   = (_Float16*)(ws + WS_E2);
    float*  en2    = ws + WS_EN2;
    int*    minI2  = (int*)(ws + WS_MINI2);
    float*  bins   = ws + WS_BINS;
    float*  esum   = ws + WS_ESUM;
    float*  lpart  = ws + WS_LPART;

    k_prep_z<<<NV / 4, 256, 0, stream>>>(z, z2);
    k_prep_e<<<NE / 4, 256, 0, stream>>>(emb, e2, en2);
    k_dist<<<dim3(NV / BZ, Q), 256, 0, stream>>>(z2, e2, en2, minI2);
    // bins+esum zeroing must follow k_dist (they alias the z2 region)
    hipMemsetAsync(bins, 0, ((size_t)NE + (size_t)NE * D) * sizeof(float), stream);
    k_gather<<<NV / 4, 256, 0, stream>>>(z, emb, en2, minI2,
                                         out + OUT_ZQ, out + OUT_IDX, bins, esum, lpart);
    k_loss<<<1, 256, 0, stream>>>(lpart, out + OUT_LOSS);
    k_codebook<<<NE / 4, 256, 0, stream>>>(emb, csz, eavg, bins, esum,
                                           out + OUT_EMB, out + OUT_CS, out + OUT_EAVG);
}